// Round 3
// baseline (196.371 us; speedup 1.0000x reference)
//
#include <hip/hip_runtime.h>
#include <stdint.h>

// Problem: out[M=2048(size_out), N=8192(batch)] = W[K,M]^T @ X[N,K]^T
//   out[m,n] = sum_k W[k,m] * X[n,k]
#define M_DIM 2048
#define N_DIM 8192
#define K_DIM 2048

typedef _Float16 f16x8  __attribute__((ext_vector_type(8)));
typedef float    f32x16 __attribute__((ext_vector_type(16)));

// ---------------- fused prep: cvt X (blocks 0..4095) + transpose W (4096..5119) ----------------

__global__ __launch_bounds__(256) void prep(const float* __restrict__ X,
                                            const float* __restrict__ W,
                                            _Float16* __restrict__ Xb,
                                            _Float16* __restrict__ Wt) {
    __shared__ float tile[64][65];
    int b = blockIdx.x;
    if (b < 4096) {
        // X [N,K] fp32 -> Xb [N,K] f16, 16 elems/thread
        size_t i = ((size_t)b * 256 + threadIdx.x) * 16;
        float4 a0 = *(const float4*)(X + i);
        float4 a1 = *(const float4*)(X + i + 4);
        float4 a2 = *(const float4*)(X + i + 8);
        float4 a3 = *(const float4*)(X + i + 12);
        f16x8 h0, h1;
        h0[0] = (_Float16)a0.x; h0[1] = (_Float16)a0.y; h0[2] = (_Float16)a0.z; h0[3] = (_Float16)a0.w;
        h0[4] = (_Float16)a1.x; h0[5] = (_Float16)a1.y; h0[6] = (_Float16)a1.z; h0[7] = (_Float16)a1.w;
        h1[0] = (_Float16)a2.x; h1[1] = (_Float16)a2.y; h1[2] = (_Float16)a2.z; h1[3] = (_Float16)a2.w;
        h1[4] = (_Float16)a3.x; h1[5] = (_Float16)a3.y; h1[6] = (_Float16)a3.z; h1[7] = (_Float16)a3.w;
        *(f16x8*)(Xb + i) = h0;
        *(f16x8*)(Xb + i + 8) = h1;
    } else {
        // W [K,M] fp32 -> Wt [M,K] f16, 64x64 tile
        b -= 4096;                          // 1024 blocks
        const int m0 = (b & 31) * 64;
        const int k0 = (b >> 5) * 64;
        const int tx = threadIdx.x & 63;    // m
        const int ty = threadIdx.x >> 6;    // 0..3
#pragma unroll
        for (int i = 0; i < 64; i += 4)
            tile[ty + i][tx] = W[(size_t)(k0 + ty + i) * M_DIM + m0 + tx];  // tile[k][m]
        __syncthreads();
        const int kc = threadIdx.x & 7;     // k chunk (8 elems)
        const int mr = threadIdx.x >> 3;    // 0..31
#pragma unroll
        for (int half = 0; half < 2; ++half) {
            const int m = mr + half * 32;
            f16x8 v;
#pragma unroll
            for (int j = 0; j < 8; ++j) v[j] = (_Float16)tile[kc * 8 + j][m];
            *(f16x8*)(Wt + (size_t)(m0 + m) * K_DIM + k0 + kc * 8) = v;     // 16B store
        }
    }
}

// ---------------- f16 MFMA GEMM: 128x256 block, 64x128 wave tile, 32x32x16 MFMA ----------------

__device__ __forceinline__ void load_to_lds16(const void* g, void* l) {
    __builtin_amdgcn_global_load_lds(
        (__attribute__((address_space(1))) void*)(uintptr_t)g,
        (__attribute__((address_space(3))) void*)l,
        16, 0, 0);
}

// A = Wt [M,K] f16 (K-contiguous), B = Xb [N,K] f16 (K-contiguous), C [M,N] fp32
//
// LDS tiles: rows of BK=64 f16 (128 B = 8 chunks of 16 B). Swizzle: LDS slot
// (r, c) holds global chunk (r, c ^ sigma(r)), sigma(r) = (r>>2)&7.
//  - staging: lane-slot (i*32 + t>>3, t&7) -> global chunk (t&7)^(t>>5)
//    (issue-independent since issues step rows by 32).
//  - frag reads (32 rows r = base + lane&31, base % 32 == 0): granule
//    (lane&3)*8 + (q ^ (lane>>2)&7) covers all 32 bank groups; lanes 32..63
//    duplicate them 2-way (free, m136).
__global__ __launch_bounds__(256, 2) void gemm_f16(const _Float16* __restrict__ A,
                                                   const _Float16* __restrict__ B,
                                                   float* __restrict__ C) {
    constexpr int BK = 64;
    __shared__ _Float16 As[128 * BK];   // 16 KB
    __shared__ _Float16 Bs[256 * BK];   // 32 KB

    const int tid  = threadIdx.x;
    const int wave = tid >> 6;
    const int lane = tid & 63;

    // XCD swizzle: 512 blocks, 64 per XCD -> each XCD sees 4 bn columns (4 MB of B ~ L2)
    const int bid = ((blockIdx.x & 7) << 6) | (blockIdx.x >> 3);
    const int bm = bid & 15;           // M_DIM/128
    const int bn = bid >> 4;           // N_DIM/256
    const int wm = wave & 1;           // 2x2 wave grid; wave tile 64(m) x 128(n)
    const int wn = wave >> 1;
    const int l31 = lane & 31;
    const int kh  = lane >> 5;         // k-half within a kstep

    // staging addressing
    const int srow = tid >> 3;                       // 0..31
    const int scol = ((tid & 7) ^ (tid >> 5)) * 8;   // swizzled global k offset (elems)
    const _Float16* ga = A + (size_t)(bm * 128 + srow) * K_DIM + scol;
    const _Float16* gb = B + (size_t)(bn * 256 + srow) * K_DIM + scol;
    char* la = (char*)As + wave * 1024;              // + issue*4096
    char* lb = (char*)Bs + wave * 1024;

    // fragment addressing: A row = wm*64 + mb*32 + l31; B row = wn*128 + nb*32 + l31
    // chunk q = ks*2 + kh lives at byte col ((q ^ ((lane>>2)&7)) * 16
    const int sig = (lane >> 2) & 7;

    f32x16 acc[2][4] = {};

    for (int kt = 0; kt < K_DIM / BK; ++kt) {
        __syncthreads();               // prev iter's LDS reads done
#pragma unroll
        for (int i = 0; i < 4; ++i)
            load_to_lds16(ga + (size_t)(i * 32) * K_DIM, la + i * 4096);
#pragma unroll
        for (int i = 0; i < 8; ++i)
            load_to_lds16(gb + (size_t)(i * 32) * K_DIM, lb + i * 4096);
        ga += BK; gb += BK;
        __syncthreads();               // vmcnt drained: staged data visible

#pragma unroll
        for (int ks = 0; ks < 4; ++ks) {
            const int c = ((ks * 2 + kh) ^ sig) * 16;     // byte offset of 16B chunk
            f16x8 af[2], bf[4];
#pragma unroll
            for (int mb = 0; mb < 2; ++mb)
                af[mb] = *(const f16x8*)((const char*)As + (wm * 64 + mb * 32 + l31) * 128 + c);
#pragma unroll
            for (int nb = 0; nb < 4; ++nb)
                bf[nb] = *(const f16x8*)((const char*)Bs + (wn * 128 + nb * 32 + l31) * 128 + c);
#pragma unroll
            for (int mb = 0; mb < 2; ++mb)
#pragma unroll
                for (int nb = 0; nb < 4; ++nb)
                    acc[mb][nb] = __builtin_amdgcn_mfma_f32_32x32x16_f16(
                        af[mb], bf[nb], acc[mb][nb], 0, 0, 0);
        }
    }

    // epilogue: D col(n) = lane&31, row(m) = (reg&3) + 8*(reg>>2) + 4*(lane>>5)
    const int cn0 = bn * 256 + wn * 128 + l31;
    const int rm0 = bm * 128 + wm * 64 + 4 * kh;
#pragma unroll
    for (int mb = 0; mb < 2; ++mb)
#pragma unroll
        for (int nb = 0; nb < 4; ++nb) {
            float* cp = C + (size_t)(rm0 + mb * 32) * N_DIM + cn0 + nb * 32;
#pragma unroll
            for (int r = 0; r < 16; ++r) {
                const int roff = (r & 3) + 8 * (r >> 2);
                cp[(size_t)roff * N_DIM] = acc[mb][nb][r];
            }
        }
}

// ---------------- fp32 fallback (only if ws too small) ----------------

__global__ __launch_bounds__(256) void gemm_f32_fallback(const float* __restrict__ X,
                                                         const float* __restrict__ W,
                                                         float* __restrict__ C) {
    __shared__ float As2[16][64];  // As2[k][m]
    __shared__ float Bs2[16][64];  // Bs2[k][n]
    const int tid = threadIdx.x;
    const int bm = blockIdx.x & 31;
    const int bn = blockIdx.x >> 5;
    const int tm = tid & 15, tn = tid >> 4;
    float c[4][4] = {};
    for (int k0 = 0; k0 < K_DIM; k0 += 16) {
        __syncthreads();
#pragma unroll
        for (int i = 0; i < 4; ++i) {
            int e = i * 256 + tid;
            As2[e >> 6][e & 63] = W[(size_t)(k0 + (e >> 6)) * M_DIM + bm * 64 + (e & 63)];
        }
#pragma unroll
        for (int i = 0; i < 4; ++i) {
            int e = i * 256 + tid;
            Bs2[e & 15][e >> 4] = X[(size_t)(bn * 64 + (e >> 4)) * K_DIM + k0 + (e & 15)];
        }
        __syncthreads();
#pragma unroll
        for (int kk = 0; kk < 16; ++kk)
#pragma unroll
            for (int i = 0; i < 4; ++i)
#pragma unroll
                for (int j = 0; j < 4; ++j)
                    c[i][j] += As2[kk][tm * 4 + i] * Bs2[kk][tn * 4 + j];
    }
#pragma unroll
    for (int i = 0; i < 4; ++i)
#pragma unroll
        for (int j = 0; j < 4; ++j)
            C[(size_t)(bm * 64 + tm * 4 + i) * N_DIM + bn * 64 + tn * 4 + j] = c[i][j];
}

// ---------------- launch ----------------

extern "C" void kernel_launch(void* const* d_in, const int* in_sizes, int n_in,
                              void* d_out, int out_size, void* d_ws, size_t ws_size,
                              hipStream_t stream) {
    const float* X = (const float*)d_in[0];  // [8192, 2048]
    const float* W = (const float*)d_in[1];  // [2048, 2048]
    // d_in[2] = bias: intentionally unused (reference discards it)
    float* C = (float*)d_out;                // [2048, 8192]

    const size_t xb_bytes = (size_t)N_DIM * K_DIM * sizeof(_Float16);  // 32 MB
    const size_t wt_bytes = (size_t)M_DIM * K_DIM * sizeof(_Float16);  //  8 MB

    if (ws_size >= xb_bytes + wt_bytes) {
        _Float16* Xb = (_Float16*)d_ws;
        _Float16* Wt = (_Float16*)((char*)d_ws + xb_bytes);
        prep<<<4096 + 1024, 256, 0, stream>>>(X, W, Xb, Wt);
        gemm_f16<<<(M_DIM / 128) * (N_DIM / 256), 256, 0, stream>>>(Wt, Xb, C);
    } else {
        gemm_f32_fallback<<<(M_DIM / 64) * (N_DIM / 64), 256, 0, stream>>>(X, W, C);
    }
}